// Round 1
// baseline (76.186 us; speedup 1.0000x reference)
//
#include <hip/hip_runtime.h>

#define NB 524288
#define ND 8
#define NC 32
#define EPSV 1e-4f
#define DTB 0.12f      // DT * BETA
#define CLAMPV 3.0f
#define NSTEPS 4

__global__ __launch_bounds__(256) void pm_kernel(
    const float* __restrict__ z_in,
    const float* __restrict__ centers,
    const float* __restrict__ mus,
    float* __restrict__ out)
{
    // Stage centers (32x8 f32 = 1KB) and mus (128B) in LDS; reads are
    // wave-uniform -> broadcast, conflict-free.
    __shared__ float4 sc[NC * 2];
    __shared__ float  smu[NC];

    const int tid = threadIdx.x;
    if (tid < NC * 2) sc[tid] = ((const float4*)centers)[tid];
    if (tid < NC)     smu[tid] = mus[tid];
    __syncthreads();

    const int i = blockIdx.x * 256 + tid;
    const float4* zp = (const float4*)z_in;
    float4 a = zp[(size_t)i * 2];
    float4 b = zp[(size_t)i * 2 + 1];
    float z[8] = {a.x, a.y, a.z, a.w, b.x, b.y, b.z, b.w};

    #pragma unroll 1
    for (int s = 0; s < NSTEPS; ++s) {
        float n = 1.0f;
        float g[8] = {0.f, 0.f, 0.f, 0.f, 0.f, 0.f, 0.f, 0.f};
        #pragma unroll
        for (int c = 0; c < NC; ++c) {
            float4 c0 = sc[c * 2];
            float4 c1 = sc[c * 2 + 1];
            float rv[8];
            rv[0] = z[0] - c0.x; rv[1] = z[1] - c0.y;
            rv[2] = z[2] - c0.z; rv[3] = z[3] - c0.w;
            rv[4] = z[4] - c1.x; rv[5] = z[5] - c1.y;
            rv[6] = z[6] - c1.z; rv[7] = z[7] - c1.w;

            float r2 = EPSV;
            #pragma unroll
            for (int d = 0; d < 8; ++d) r2 = fmaf(rv[d], rv[d], r2);

            float rinv = rsqrtf(r2);          // v_rsq_f32
            float w    = smu[c] * rinv;       // mu / r
            n += w;
            float w3   = w * rinv * rinv;     // mu / (r * r2)
            #pragma unroll
            for (int d = 0; d < 8; ++d) g[d] = fmaf(-w3, rv[d], g[d]);
        }
        float scale = DTB / n;                // one real divide per step
        #pragma unroll
        for (int d = 0; d < 8; ++d) {
            float zn = fmaf(scale, g[d], z[d]);
            z[d] = fminf(fmaxf(zn, -CLAMPV), CLAMPV);
        }
    }

    float4 o0 = {z[0], z[1], z[2], z[3]};
    float4 o1 = {z[4], z[5], z[6], z[7]};
    float4* op = (float4*)out;
    op[(size_t)i * 2]     = o0;
    op[(size_t)i * 2 + 1] = o1;
}

extern "C" void kernel_launch(void* const* d_in, const int* in_sizes, int n_in,
                              void* d_out, int out_size, void* d_ws, size_t ws_size,
                              hipStream_t stream) {
    const float* z       = (const float*)d_in[0];
    const float* centers = (const float*)d_in[1];
    const float* mus     = (const float*)d_in[2];
    float* out           = (float*)d_out;

    dim3 block(256);
    dim3 grid(NB / 256);   // 2048 blocks
    pm_kernel<<<grid, block, 0, stream>>>(z, centers, mus, out);
}